// Round 13
// baseline (79.861 us; speedup 1.0000x reference)
//
#include <hip/hip_runtime.h>
#include <hip/hip_bf16.h>
#include <stdint.h>

typedef __attribute__((ext_vector_type(4))) float f32x4;
typedef __attribute__((ext_vector_type(8))) short bf16x8;

#define NCH  128
#define NREL 8

__device__ __forceinline__ unsigned short f2bf(float f) {
    unsigned u = __builtin_bit_cast(unsigned, f);
    u += 0x7fffu + ((u >> 16) & 1u);          // RNE to bf16
    return (unsigned short)(u >> 16);
}

__device__ __forceinline__ bool mask_used(const unsigned char* um, int stride, int s) {
    if (stride == 1) return um[s] != 0;
    if (stride == 4) return ((const int*)um)[s] != 0;
    return ((const long long*)um)[s] != 0;
}

// ---------------------------------------------------------------------------
// K1 (512 blocks x 256): pure Wb convert, 1 element/thread.
// Block 0 detects used_mask element width -> cn[1]. No classify, no tickets.
// ---------------------------------------------------------------------------
__global__ __launch_bounds__(256)
void k_prep(const float* __restrict__ W, unsigned short* __restrict__ Wb,
            int* __restrict__ cn, const unsigned char* __restrict__ um_raw) {
    const int t = threadIdx.x;
    const int o = blockIdx.x * 256 + t;
    {
        const int kk  = o & 31;
        const int col = (o >> 5) & (NCH - 1);
        const int kt  = o >> 12;
        Wb[o] = f2bf(W[(kt * 32 + kk) * NCH + col]);
    }
    if (blockIdx.x == 0) {
        __shared__ unsigned sA, sB;
        if (t == 0) { sA = 0; sB = 0; }
        __syncthreads();
        unsigned a = 0, b = 0;
        #pragma unroll 4
        for (int p = t; p < 1024; p += 256) {
            const unsigned v = um_raw[p];
            if ((p & 3) != 0) a |= v;   // bool kept 1B -> data off 4-align
            if ((p & 7) == 4) b |= v;   // int32 -> data at 4 mod 8
        }
        if (a) atomicOr(&sA, 1u);
        if (b) atomicOr(&sB, 1u);
        __syncthreads();
        if (t == 0) cn[1] = sA ? 1 : (sB ? 4 : 8);
    }
}

// ---------------------------------------------------------------------------
// K2 (self-contained, 1024 blocks x 512): block w owns nodes [w*64, w*64+64).
//  1. wave 0 ballot-classifies the 64 nodes (cached vs non-cached).
//  2. copy role: 16 half-waves x 4 rounds copy cached rows (~53) to out.
//  3. compute role: groups of 16 non-cached nodes (avg 10.7, >16 in ~4% of
//     blocks) through the proven pipeline: 16 row-gathers in flight ->
//     8-way select-accumulate -> bf16 swizzled LDS -> MFMA vs Wb ->
//     LDS-staged contiguous 512B row stores.
// No glist, no tickets, no memset, no inter-kernel handoff; stream-bound
// copy and latency-bound gather overlap via 8 waves/block x 2 blocks/CU.
// ---------------------------------------------------------------------------
__global__ __launch_bounds__(512, 2)
void k_fused(const float* __restrict__ x, const unsigned short* __restrict__ Wb,
             const int* __restrict__ ptr, const int* __restrict__ idx,
             const int* __restrict__ et, const unsigned char* __restrict__ um,
             const int* __restrict__ cn, const float* __restrict__ hb,
             const int* __restrict__ hm, const int* __restrict__ hs,
             float* __restrict__ out, int num_node) {
    __shared__ __align__(16) char As[16 * NREL * NCH * 2];   // 32 KB, XOR-swizzled
    __shared__ int   cList[64], ncList[64];
    __shared__ int   nC_s, nNC_s;
    __shared__ int   nidg[16];
    __shared__ float invdeg[16];

    const int t  = threadIdx.x;
    const int n0 = blockIdx.x * 64;

    if (t < 64) {                                  // wave 0 classifies
        const int n = n0 + t;
        const bool valid  = n < num_node;
        const bool cached = valid && (hs[0] > 0) && (hm[n] != -1);
        const bool nc     = valid && !cached;
        const unsigned long long mC  = __ballot(cached);
        const unsigned long long mNC = __ballot(nc);
        const unsigned long long below = (1ull << t) - 1;
        if (cached) cList[__popcll(mC & below)]   = n;
        if (nc)     ncList[__popcll(mNC & below)] = n;
        if (t == 0) { nC_s = __popcll(mC); nNC_s = __popcll(mNC); }
    }
    __syncthreads();
    const int nC  = nC_s;
    const int nNC = nNC_s;
    const int hw    = t >> 5;       // half-wave id 0..15
    const int l     = t & 31;       // lane in half-wave; owns channels 4l..4l+3
    const int lbase = t & 32;       // half-wave base within its wave
    const int mstride = cn[1];

    // ---- copy role: rows hw, hw+16, hw+32, hw+48 of the cached list ----
    {
        int   node[4];
        f32x4 v[4];
        #pragma unroll 4
        for (int j = 0; j < 4; ++j) {
            const int i = hw + j * 16;
            node[j] = (i < nC) ? cList[i] : -1;
            if (node[j] >= 0)
                v[j] = *(const f32x4*)(hb + (long)node[j] * NCH + l * 4);
        }
        #pragma unroll 4
        for (int j = 0; j < 4; ++j) {
            if (node[j] >= 0)
                __builtin_nontemporal_store(v[j],
                    (f32x4*)(out + (long)node[j] * NCH + l * 4));
        }
    }

    // ---- compute role: groups of 16 non-cached nodes ----
    const int nGroups = (nNC + 15) >> 4;           // 0 if nNC==0
    for (int g = 0; g < nGroups; ++g) {
        if (t < 16) {
            const int i = g * 16 + t;
            nidg[t]   = (i < nNC) ? ncList[i] : -1;
            invdeg[t] = 0.0f;
        }
        __syncthreads();

        const int n = nidg[hw];
        if (n >= 0) {
            const int p0 = ptr[n], p1 = ptr[n + 1];
            const int deg = p1 - p0;
            if (l == 0) invdeg[hw] = (deg > 0) ? 1.0f / (float)deg : 0.0f;
            // lanes 0..15 of the half-wave fetch edge meta, pack (rel<<24)|src
            int myPk = NREL << 24;
            if (l < 16 && (p0 + l) < p1) {
                const int e  = p0 + l;
                const int s  = idx[e];
                const int tt = et[e];
                myPk = s | (((mask_used(um, mstride, s) && tt >= 0 && tt < NREL)
                             ? tt : NREL) << 24);
            }
            // all 16 row-gathers in flight before any consumption
            int   pk[16];
            f32x4 xv[16];
            #pragma unroll 16
            for (int e = 0; e < 16; ++e) {
                pk[e] = __shfl(myPk, lbase + e, 64);
                xv[e] = *(const f32x4*)(x + (long)(pk[e] & 0xFFFFFF) * NCH + l * 4);
            }
            float acc[NREL][4];
            #pragma unroll
            for (int q = 0; q < NREL; ++q)
                #pragma unroll
                for (int j = 0; j < 4; ++j) acc[q][j] = 0.0f;
            #pragma unroll 16
            for (int e = 0; e < 16; ++e) {
                const int r = pk[e] >> 24;
                #pragma unroll
                for (int q = 0; q < NREL; ++q) {
                    const float sel = (r == q) ? 1.0f : 0.0f;
                    acc[q][0] += sel * xv[e].x;
                    acc[q][1] += sel * xv[e].y;
                    acc[q][2] += sel * xv[e].z;
                    acc[q][3] += sel * xv[e].w;
                }
            }
            for (int e = p0 + 16; e < p1; ++e) {   // rare: deg > 16
                const int s  = idx[e];
                const int tt = et[e];
                if (mask_used(um, mstride, s) && tt >= 0 && tt < NREL) {
                    const f32x4 w = *(const f32x4*)(x + (long)s * NCH + l * 4);
                    #pragma unroll
                    for (int q = 0; q < NREL; ++q) {
                        const float sel = (tt == q) ? 1.0f : 0.0f;
                        acc[q][0] += sel * w.x;
                        acc[q][1] += sel * w.y;
                        acc[q][2] += sel * w.z;
                        acc[q][3] += sel * w.w;
                    }
                }
            }
            // bf16 pack -> swizzled LDS A[hw][k], k = q*128 + 4l + j
            #pragma unroll
            for (int q = 0; q < NREL; ++q) {
                ushort4 pkv;
                pkv.x = f2bf(acc[q][0]); pkv.y = f2bf(acc[q][1]);
                pkv.z = f2bf(acc[q][2]); pkv.w = f2bf(acc[q][3]);
                const int eb   = (q * NCH + l * 4) * 2;
                const int addr = (hw * 2048 + eb) ^ ((hw & 7) << 4);
                *(ushort4*)(As + addr) = pkv;
            }
        }
        __syncthreads();

        // MFMA: 8 waves; wave wv covers output cols [wv*16, wv*16+16)
        const int wv   = t >> 6;
        const int lane = t & 63;
        const int row  = lane & 15;
        const int koff = (lane >> 4) * 8;
        const int col0 = wv * 16 + row;
        f32x4 c0 = {0.f, 0.f, 0.f, 0.f};
        #pragma unroll 8
        for (int kt = 0; kt < 32; ++kt) {
            const int aaddr = (row * 2048 + (kt * 32 + koff) * 2) ^ ((row & 7) << 4);
            const bf16x8 a  = *(const bf16x8*)(As + aaddr);
            const bf16x8 b0 = *(const bf16x8*)(Wb + ((kt * NCH + col0) << 5) + koff);
            c0 = __builtin_amdgcn_mfma_f32_16x16x32_bf16(a, b0, c0, 0, 0, 0);
        }

        // epilogue: stage scaled C in LDS, store contiguous 512B rows (nt)
        __syncthreads();
        float* Cs = (float*)As;            // reuse As as float Cs[16][128]
        {
            const int r4 = (lane >> 4) * 4;
            #pragma unroll
            for (int j = 0; j < 4; ++j) {
                const int rr = r4 + j;
                Cs[rr * NCH + col0] = c0[j] * invdeg[rr];
            }
        }
        __syncthreads();
        {
            const int nn = nidg[hw];
            if (nn >= 0) {
                const f32x4 vv = *(const f32x4*)(Cs + hw * NCH + l * 4);
                __builtin_nontemporal_store(vv,
                    (f32x4*)(out + (long)nn * NCH + l * 4));
            }
        }
        __syncthreads();                   // As reusable for next group
    }
}

extern "C" void kernel_launch(void* const* d_in, const int* in_sizes, int n_in,
                              void* d_out, int out_size, void* d_ws, size_t ws_size,
                              hipStream_t stream) {
    const float*         x   = (const float*)d_in[0];
    const float*         W   = (const float*)d_in[1];
    const float*         hb  = (const float*)d_in[2];
    const int*           ptr = (const int*)d_in[3];
    const int*           idx = (const int*)d_in[4];
    const int*           et  = (const int*)d_in[5];
    const unsigned char* um  = (const unsigned char*)d_in[6];
    const int*           hm  = (const int*)d_in[7];
    const int*           hs  = (const int*)d_in[8];
    float* out = (float*)d_out;

    const int num_node = in_sizes[7];           // history_map length

    // ws layout: cn (256B: [1]=mask width) | Wb
    int* cn = (int*)d_ws;
    unsigned short* Wb = (unsigned short*)((char*)d_ws + 256);

    k_prep<<<512, 256, 0, stream>>>(W, Wb, cn, um);
    k_fused<<<(num_node + 63) / 64, 512, 0, stream>>>(
        x, Wb, ptr, idx, et, um, cn, hb, hm, hs, out, num_node);
}